// Round 1
// baseline (29.440 us; speedup 1.0000x reference)
//
#include <hip/hip_runtime.h>

#define BLOCK 256
#define EPSF 1e-8f

// Main kernel: one thread per box. Computes L1 partial and (1-giou) partial,
// block-reduces both into partials[blockIdx*2 + {0,1}].
__global__ __launch_bounds__(BLOCK) void box_loss_main(
    const float* __restrict__ box, const float* __restrict__ tgt,
    const float* __restrict__ wgt, int n, float* __restrict__ partials)
{
    // Polygon ping-pong buffers: [buf][coord][vert][tid]  (32 KB)
    __shared__ float sp[2][2][8][BLOCK];
    __shared__ float red[2][BLOCK / 64];

    const int tid = threadIdx.x;
    float sum_box = 0.f, sum_giou = 0.f;

    for (int i = blockIdx.x * BLOCK + tid; i < n; i += gridDim.x * BLOCK) {
        const float* bp = box + (size_t)i * 11;
        const float* tp = tgt + (size_t)i * 11;
        const float* wp = wgt + (size_t)i * 11;
        float b[11], t[11], w[11];
#pragma unroll
        for (int j = 0; j < 11; ++j) { b[j] = bp[j]; t[j] = tp[j]; w[j] = wp[j]; }

        // ---- L1 box loss ----
        float lb = 0.f;
#pragma unroll
        for (int j = 0; j < 11; ++j) lb += fabsf(b[j] - t[j]) * w[j];
        sum_box += lb;

        // ---- decode to BEV: [cx, cy, w, l, yaw] ----
        float cx1 = b[0], cy1 = b[1];
        float w1 = expf(b[3]), l1 = expf(b[4]);
        float yaw1 = atan2f(b[6], b[7]);
        float cx2 = t[0], cy2 = t[1];
        float w2 = expf(t[3]), l2 = expf(t[4]);
        float yaw2 = atan2f(t[6], t[7]);

        float s1 = sinf(yaw1), c1 = cosf(yaw1);
        float s2 = sinf(yaw2), c2 = cosf(yaw2);
        float hx1 = 0.5f * w1, hy1 = 0.5f * l1;
        float hx2 = 0.5f * w2, hy2 = 0.5f * l2;

        // corners CCW: (-dx,-dy),(dx,-dy),(dx,dy),(-dx,dy) rotated + translated
        const float LX[4] = { -1.f, 1.f, 1.f, -1.f };
        const float LY[4] = { -1.f, -1.f, 1.f, 1.f };
        float v1x[4], v1y[4], v2x[4], v2y[4];
#pragma unroll
        for (int k = 0; k < 4; ++k) {
            float lx = LX[k] * hx1, ly = LY[k] * hy1;
            v1x[k] = lx * c1 - ly * s1 + cx1;
            v1y[k] = lx * s1 + ly * c1 + cy1;
            float mx = LX[k] * hx2, my = LY[k] * hy2;
            v2x[k] = mx * c2 - my * s2 + cx2;
            v2y[k] = mx * s2 + my * c2 + cy2;
        }

        // enclosing AABB over all 8 original vertices
        float minx = v1x[0], maxx = v1x[0], miny = v1y[0], maxy = v1y[0];
#pragma unroll
        for (int k = 1; k < 4; ++k) {
            minx = fminf(minx, v1x[k]); maxx = fmaxf(maxx, v1x[k]);
            miny = fminf(miny, v1y[k]); maxy = fmaxf(maxy, v1y[k]);
        }
#pragma unroll
        for (int k = 0; k < 4; ++k) {
            minx = fminf(minx, v2x[k]); maxx = fmaxf(maxx, v2x[k]);
            miny = fminf(miny, v2y[k]); maxy = fmaxf(maxy, v2y[k]);
        }
        float enc = (maxx - minx) * (maxy - miny);

        // ---- Sutherland-Hodgman: clip rect1 by the 4 half-planes of rect2 ----
        int cnt = 4;
#pragma unroll
        for (int k = 0; k < 4; ++k) { sp[0][0][k][tid] = v1x[k]; sp[0][1][k][tid] = v1y[k]; }
        int cur = 0;
        for (int e = 0; e < 4; ++e) {
            if (cnt != 0) {
                float ax = v2x[e], ay = v2y[e];
                float bx = v2x[(e + 1) & 3], by = v2y[(e + 1) & 3];
                float ddx = bx - ax, ddy = by - ay;
                int nxt = cur ^ 1;
                int m = 0;
                float prx = sp[cur][0][cnt - 1][tid];
                float pry = sp[cur][1][cnt - 1][tid];
                bool pin = (ddx * (pry - ay) - ddy * (prx - ax)) >= 0.f;
                for (int ii = 0; ii < cnt; ++ii) {
                    float cxx = sp[cur][0][ii][tid];
                    float cyy = sp[cur][1][ii][tid];
                    bool cin = (ddx * (cyy - ay) - ddy * (cxx - ax)) >= 0.f;
                    if ((cin != pin) && m < 8) {
                        // intersection of edge prev->cur with half-plane boundary
                        float num = (ax - prx) * ddy - (ay - pry) * ddx;
                        float den = (cxx - prx) * ddy - (cyy - pry) * ddx + EPSF;
                        float tt = num / den;
                        sp[nxt][0][m][tid] = prx + tt * (cxx - prx);
                        sp[nxt][1][m][tid] = pry + tt * (cyy - pry);
                        ++m;
                    }
                    if (cin && m < 8) {
                        sp[nxt][0][m][tid] = cxx;
                        sp[nxt][1][m][tid] = cyy;
                        ++m;
                    }
                    prx = cxx; pry = cyy; pin = cin;
                }
                cnt = (m < 3) ? 0 : m;   // degenerate -> empty
                cur = nxt;
            }
        }

        // ---- shoelace area of the intersection ----
        float inter = 0.f;
        if (cnt >= 3) {
            float px0 = sp[cur][0][0][tid], py0 = sp[cur][1][0][tid];
            float prx = px0, pry = py0;
            float s = 0.f;
            for (int ii = 1; ii < cnt; ++ii) {
                float cxx = sp[cur][0][ii][tid], cyy = sp[cur][1][ii][tid];
                s += prx * cyy - pry * cxx;
                prx = cxx; pry = cyy;
            }
            s += prx * py0 - pry * px0;   // wrap
            inter = fabsf(s) * 0.5f;
        }

        float areaU = w1 * l1 + w2 * l2 - inter;
        float iou = inter / (areaU + EPSF);
        float giou = iou - (enc - areaU) / (enc + EPSF);
        sum_giou += 1.f - giou;
    }

    // ---- block reduction (wave=64) ----
#pragma unroll
    for (int off = 32; off > 0; off >>= 1) {
        sum_box  += __shfl_down(sum_box, off);
        sum_giou += __shfl_down(sum_giou, off);
    }
    const int wave = tid >> 6, lane = tid & 63;
    if (lane == 0) { red[0][wave] = sum_box; red[1][wave] = sum_giou; }
    __syncthreads();
    if (tid == 0) {
        float a = 0.f, g = 0.f;
#pragma unroll
        for (int k = 0; k < BLOCK / 64; ++k) { a += red[0][k]; g += red[1][k]; }
        partials[(size_t)blockIdx.x * 2 + 0] = a;
        partials[(size_t)blockIdx.x * 2 + 1] = g;
    }
}

// Final kernel: deterministic reduction of per-block partials + 1/af scaling.
__global__ __launch_bounds__(256) void box_loss_final(
    const float* __restrict__ partials, int nblk,
    const int* __restrict__ avg_factor, float* __restrict__ out)
{
    __shared__ float red[2][4];
    float a = 0.f, g = 0.f;
    for (int i = threadIdx.x; i < nblk; i += 256) {
        a += partials[(size_t)i * 2 + 0];
        g += partials[(size_t)i * 2 + 1];
    }
#pragma unroll
    for (int off = 32; off > 0; off >>= 1) {
        a += __shfl_down(a, off);
        g += __shfl_down(g, off);
    }
    const int wave = threadIdx.x >> 6, lane = threadIdx.x & 63;
    if (lane == 0) { red[0][wave] = a; red[1][wave] = g; }
    __syncthreads();
    if (threadIdx.x == 0) {
        float af = (float)(*avg_factor);
        if (af < 1.f) af = 1.f;
        float sa = red[0][0] + red[0][1] + red[0][2] + red[0][3];
        float sg = red[1][0] + red[1][1] + red[1][2] + red[1][3];
        out[0] = sa / af;
        out[1] = sg / af;
    }
}

extern "C" void kernel_launch(void* const* d_in, const int* in_sizes, int n_in,
                              void* d_out, int out_size, void* d_ws, size_t ws_size,
                              hipStream_t stream) {
    const float* box = (const float*)d_in[0];
    const float* tgt = (const float*)d_in[1];
    const float* wgt = (const float*)d_in[2];
    const int*   af  = (const int*)d_in[3];
    float* out = (float*)d_out;
    float* partials = (float*)d_ws;

    int n = in_sizes[0] / 11;          // number of boxes
    int nblk = 2048;
    int maxblk = (n + BLOCK - 1) / BLOCK;
    if (nblk > maxblk) nblk = maxblk;
    if (nblk < 1) nblk = 1;
    size_t need = (size_t)nblk * 2 * sizeof(float);
    if (need > ws_size) nblk = (int)(ws_size / (2 * sizeof(float)));

    hipLaunchKernelGGL(box_loss_main, dim3(nblk), dim3(BLOCK), 0, stream,
                       box, tgt, wgt, n, partials);
    hipLaunchKernelGGL(box_loss_final, dim3(1), dim3(256), 0, stream,
                       partials, nblk, af, out);
}